// Round 1
// baseline (468.282 us; speedup 1.0000x reference)
//
#include <hip/hip_runtime.h>

constexpr int TAGS = 64;
constexpr int START_T = 62;
constexpr int END_T = 63;
constexpr float NEGF = -10000.0f;
constexpr int L_DIM = 512;
constexpr int B_DIM = 1024;

__device__ __forceinline__ float lane_bcast(float x, int lane) {
    return __int_as_float(__builtin_amdgcn_readlane(__float_as_int(x), lane));
}

__device__ __forceinline__ float wave_max64(float x) {
#pragma unroll
    for (int off = 32; off >= 1; off >>= 1)
        x = fmaxf(x, __shfl_xor(x, off, 64));
    return x;
}

__device__ __forceinline__ float wave_sum64(float x) {
#pragma unroll
    for (int off = 32; off >= 1; off >>= 1)
        x += __shfl_xor(x, off, 64);
    return x;
}

// One wave per batch item. lane = destination tag (t_new).
// Scan step: new[i] = feat[i] + M + log( sum_j E[i,j] * exp(alpha[j]-M) ),
// E = exp(transition) precomputed (constant over steps/batches).
__global__ __launch_bounds__(256, 1) void crf_fused(
    const float* __restrict__ feats,
    const int* __restrict__ tags,
    const float* __restrict__ mask,
    const float* __restrict__ trans,
    float* __restrict__ out)
{
    __shared__ float sE[TAGS][TAGS + 1];   // +1 pad: conflict-free row reads
    const int lane = threadIdx.x;          // t_new
    const int wid  = threadIdx.y;
    const int b    = blockIdx.x * 4 + wid; // batch item for this wave
    const int tid  = wid * 64 + lane;

    // Stage E = exp(transition) into LDS (coalesced read, one-time).
#pragma unroll
    for (int k = 0; k < (TAGS * TAGS) / 256; ++k) {
        int idx = tid + 256 * k;
        sE[idx >> 6][idx & 63] = expf(trans[idx]);   // exp(-10000) -> 0 exactly
    }
    __syncthreads();

    // Each lane caches its E row in registers (64 VGPRs, static indexing).
    float Erow[TAGS];
#pragma unroll
    for (int j = 0; j < TAGS; ++j) Erow[j] = sE[lane][j];

    float a = (lane == START_T) ? 0.0f : NEGF;   // alpha0

    const float* fptr = feats + (size_t)b * TAGS + lane;
    const size_t lstride = (size_t)B_DIM * TAGS;
    float fcur = fptr[0];
    float fnxt = fptr[lstride];

#pragma unroll 1
    for (int l = 0; l < L_DIM; ++l) {
        // 2-deep prefetch of feat (independent of loop-carried alpha).
        float fpre = (l + 2 < L_DIM) ? fptr[(size_t)(l + 2) * lstride] : 0.0f;
        float m = mask[l * B_DIM + b];

        float M = wave_max64(a);
        float v = expf(a - M);                 // v[lane]; underflow -> 0 ok

        float a0 = 0.f, a1 = 0.f, a2 = 0.f, a3 = 0.f;
#pragma unroll
        for (int j = 0; j < TAGS; j += 4) {    // matvec: SGPR-broadcast FMAs
            a0 = fmaf(Erow[j + 0], lane_bcast(v, j + 0), a0);
            a1 = fmaf(Erow[j + 1], lane_bcast(v, j + 1), a1);
            a2 = fmaf(Erow[j + 2], lane_bcast(v, j + 2), a2);
            a3 = fmaf(Erow[j + 3], lane_bcast(v, j + 3), a3);
        }
        float ssum = (a0 + a1) + (a2 + a3);

        float na = fcur + M + logf(ssum);      // log(0) = -inf for t_new=START
        na = fmaxf(na, -1e30f);                // keep finite: blend would NaN on -inf*0
        a = na * m + a * (1.0f - m);           // exact reference blend semantics

        fcur = fnxt;
        fnxt = fpre;
    }

    // allpath = LSE_i(alpha[i] + trans[END,i])
    float x = a + trans[END_T * TAGS + lane];
    float Mx = wave_max64(x);
    float ex = expf(x - Mx);
    float S = wave_sum64(ex);
    float allp = Mx + logf(S);

    // realpath: lanes split the L dimension (8 steps each), then wave-reduce.
    float sc = 0.0f, lensum = 0.0f;
#pragma unroll
    for (int k = 0; k < L_DIM / 64; ++k) {
        int l = lane + 64 * k;
        int tg = tags[l * B_DIM + b];
        int pv = (l == 0) ? START_T : tags[(l - 1) * B_DIM + b];
        float m = mask[l * B_DIM + b];
        float emit = feats[((size_t)l * B_DIM + b) * TAGS + tg];
        float tr = trans[tg * TAGS + pv];
        sc += (emit + tr) * m;
        lensum += m;
    }
    sc = wave_sum64(sc);
    lensum = wave_sum64(lensum);
    int len = (int)lensum;                          // mask sum is exact in fp32
    int last_tag = (len == 0) ? START_T : tags[(len - 1) * B_DIM + b];
    float realp = sc + trans[END_T * TAGS + last_tag];

    if (lane == 0) out[b] = allp - realp;
}

extern "C" void kernel_launch(void* const* d_in, const int* in_sizes, int n_in,
                              void* d_out, int out_size, void* d_ws, size_t ws_size,
                              hipStream_t stream) {
    const float* feats = (const float*)d_in[0];
    const int*   tags  = (const int*)d_in[1];
    const float* mask  = (const float*)d_in[2];
    const float* trans = (const float*)d_in[3];
    float* out = (float*)d_out;

    dim3 block(64, 4, 1);          // 4 waves/block, one batch item each
    dim3 grid(B_DIM / 4, 1, 1);    // 256 blocks -> ~1 block per CU
    hipLaunchKernelGGL(crf_fused, grid, block, 0, stream,
                       feats, tags, mask, trans, out);
}

// Round 2
// 406.285 us; speedup vs baseline: 1.1526x; 1.1526x over previous
//
#include <hip/hip_runtime.h>

constexpr int TAGS = 64;
constexpr int START_T = 62;
constexpr int END_T = 63;
constexpr float NEGF = -10000.0f;
constexpr int L_DIM = 512;
constexpr int B_DIM = 1024;

__device__ __forceinline__ float lane_bcast(float x, int lane) {
    return __int_as_float(__builtin_amdgcn_readlane(__float_as_int(x), lane));
}

__device__ __forceinline__ float wave_max64(float x) {
#pragma unroll
    for (int off = 32; off >= 1; off >>= 1)
        x = fmaxf(x, __shfl_xor(x, off, 64));
    return x;
}

__device__ __forceinline__ float wave_sum64(float x) {
#pragma unroll
    for (int off = 32; off >= 1; off >>= 1)
        x += __shfl_xor(x, off, 64);
    return x;
}

// One wave per batch item. lane = destination tag (t_new).
// Scan step: new[i] = feat[i] + M + log( sum_j E[i,j] * exp(alpha[j]-M) ),
// E = exp(transition) precomputed. M is a RUNNING wave-uniform offset
// (alpha[0] of the previous step) instead of an exact per-step max:
// any wave-uniform M cancels exactly; only over/underflow matters, and
// finite alphas stay within ~+-10 of each other (<< exp range 87).
__global__ __launch_bounds__(256, 1) void crf_fused(
    const float* __restrict__ feats,
    const int* __restrict__ tags,
    const float* __restrict__ mask,
    const float* __restrict__ trans,
    float* __restrict__ out)
{
    __shared__ float sE[TAGS][TAGS + 1];   // +1 pad: conflict-free b32 access
    const int lane = threadIdx.x;          // t_new
    const int wid  = threadIdx.y;
    const int b    = blockIdx.x * 4 + wid; // batch item for this wave
    const int tid  = wid * 64 + lane;

    // Stage E = exp(transition) into LDS (one-time; precise expf for the table).
#pragma unroll
    for (int k = 0; k < (TAGS * TAGS) / 256; ++k) {
        int idx = tid + 256 * k;
        sE[idx >> 6][idx & 63] = expf(trans[idx]);   // exp(-10000) -> 0 exactly
    }
    __syncthreads();

    // Each lane caches its E row in registers. The empty asm makes each value
    // opaque so the compiler CANNOT sink the LDS reads back into the loop
    // (R1 showed VGPR=48 -> it had rematerialized 64 ds_reads per step).
    float Erow[TAGS];
#pragma unroll
    for (int j = 0; j < TAGS; ++j) Erow[j] = sE[lane][j];
#pragma unroll
    for (int j = 0; j < TAGS; ++j) asm volatile("" : "+v"(Erow[j]));

    float a = (lane == START_T) ? 0.0f : NEGF;   // alpha0
    float M = 0.0f;                              // true max of alpha0 (START lane)

    const float* fptr = feats + (size_t)b * TAGS + lane;
    const size_t fstride = (size_t)B_DIM * TAGS;
    const float* mptr = mask + b;

    float f0 = fptr[0];
    float f1 = fptr[fstride];
    float m0 = mptr[0];
    float m1 = mptr[B_DIM];

#pragma unroll 2
    for (int l = 0; l < L_DIM; ++l) {
        // 2-deep prefetch (independent of the loop-carried chain).
        float f2 = (l + 2 < L_DIM) ? fptr[(size_t)(l + 2) * fstride] : 0.0f;
        float m2 = (l + 2 < L_DIM) ? mptr[(size_t)(l + 2) * B_DIM] : 0.0f;

        float v = __expf(a - M);               // hw v_exp path; underflow->0 ok

        float a0 = 0.f, a1 = 0.f, a2 = 0.f, a3 = 0.f;
#pragma unroll
        for (int j = 0; j < TAGS; j += 4) {    // matvec: SGPR-broadcast FMAs
            a0 = fmaf(Erow[j + 0], lane_bcast(v, j + 0), a0);
            a1 = fmaf(Erow[j + 1], lane_bcast(v, j + 1), a1);
            a2 = fmaf(Erow[j + 2], lane_bcast(v, j + 2), a2);
            a3 = fmaf(Erow[j + 3], lane_bcast(v, j + 3), a3);
        }
        float ssum = (a0 + a1) + (a2 + a3);

        float na = f0 + M + __logf(ssum);      // log(0) = -inf for t_new=START
        na = fmaxf(na, -1e30f);                // keep finite: blend would NaN on -inf*0
        a = na * m0 + a * (1.0f - m0);         // exact when m is 0 or 1

        M = lane_bcast(a, 0);                  // running offset: 1 instr, not 6 shfls

        f0 = f1; f1 = f2;
        m0 = m1; m1 = m2;
    }

    // allpath = LSE_i(alpha[i] + trans[END,i])  (one-time: exact max is fine)
    float x = a + trans[END_T * TAGS + lane];
    float Mx = wave_max64(x);
    float ex = __expf(x - Mx);
    float S = wave_sum64(ex);
    float allp = Mx + __logf(S);

    // realpath: lanes split the L dimension (8 steps each), then wave-reduce.
    float sc = 0.0f, lensum = 0.0f;
#pragma unroll
    for (int k = 0; k < L_DIM / 64; ++k) {
        int l = lane + 64 * k;
        int tg = tags[l * B_DIM + b];
        int pv = (l == 0) ? START_T : tags[(l - 1) * B_DIM + b];
        float m = mask[l * B_DIM + b];
        float emit = feats[((size_t)l * B_DIM + b) * TAGS + tg];
        float tr = trans[tg * TAGS + pv];
        sc += (emit + tr) * m;
        lensum += m;
    }
    sc = wave_sum64(sc);
    lensum = wave_sum64(lensum);
    int len = (int)lensum;                          // mask sum is exact in fp32
    int last_tag = (len == 0) ? START_T : tags[(len - 1) * B_DIM + b];
    float realp = sc + trans[END_T * TAGS + last_tag];

    if (lane == 0) out[b] = allp - realp;
}

extern "C" void kernel_launch(void* const* d_in, const int* in_sizes, int n_in,
                              void* d_out, int out_size, void* d_ws, size_t ws_size,
                              hipStream_t stream) {
    const float* feats = (const float*)d_in[0];
    const int*   tags  = (const int*)d_in[1];
    const float* mask  = (const float*)d_in[2];
    const float* trans = (const float*)d_in[3];
    float* out = (float*)d_out;

    dim3 block(64, 4, 1);          // 4 waves/block, one batch item each
    dim3 grid(B_DIM / 4, 1, 1);    // 256 blocks -> ~1 block per CU
    hipLaunchKernelGGL(crf_fused, grid, block, 0, stream,
                       feats, tags, mask, trans, out);
}